// Round 2
// baseline (235.532 us; speedup 1.0000x reference)
//
#include <hip/hip_runtime.h>

// ---------------------------------------------------------------------------
// Cubic B-spline basis, N_BASIS=7, clamped knots [-1,-1,-1,-1,-.5,0,.5,1,1,1,1]
// Mirrors the reference Cox-de Boor recursion; guards fold at compile time.
// ---------------------------------------------------------------------------
__device__ __forceinline__ void bspline7(float x, float B[7]) {
    constexpr float t[11] = {-1.f, -1.f, -1.f, -1.f, -0.5f, 0.f, 0.5f, 1.f, 1.f, 1.f, 1.f};
    float xe = fminf(fmaxf(x, -1.f), 0.999999f);  // f32(1 - 1e-6)
    float N[10];
#pragma unroll
    for (int i = 0; i < 10; ++i)
        N[i] = (xe >= t[i] && xe < t[i + 1]) ? 1.f : 0.f;
#pragma unroll
    for (int d = 1; d <= 3; ++d) {
#pragma unroll
        for (int i = 0; i + d < 10; ++i) {
            float ld = t[i + d] - t[i];
            float rd = t[i + d + 1] - t[i + 1];
            float left  = (ld > 0.f) ? (xe - t[i]) / ld * N[i] : 0.f;
            float right = (rd > 0.f) ? (t[i + d + 1] - xe) / rd * N[i + 1] : 0.f;
            N[i] = left + right;
        }
    }
#pragma unroll
    for (int k = 0; k < 7; ++k) B[k] = N[k];
}

// ---------------------------------------------------------------------------
// Geometry constants
// ---------------------------------------------------------------------------
#define H0 384
#define H1 382            // after conv1
#define H2 380            // after conv2
#define NX (3 * H0 * H0)  // 442368 x elements
#define NP1 (H1 * H1)     // 145924 conv1 pixels
#define NP2 (H2 * H2)     // 144400 conv2 pixels (= n_in of dense1)
#define L_DENSE (NP2 * 7)       // 1010800 floats per W3 row
#define L4_DENSE (L_DENSE / 4)  // 252700 float4 per W3 row

// k0: basis of every x element -> Bx[NX][7]; also zero the 32 accumulators.
__global__ __launch_bounds__(256) void k0_basis_x(const float* __restrict__ x,
                                                  float* __restrict__ Bx,
                                                  float* __restrict__ acc32) {
    int idx = blockIdx.x * blockDim.x + threadIdx.x;
    if (blockIdx.x == 0 && threadIdx.x < 32) acc32[threadIdx.x] = 0.f;
    if (idx >= NX) return;
    float B[7];
    bspline7(x[idx], B);
#pragma unroll
    for (int k = 0; k < 7; ++k) Bx[idx * 7 + k] = B[k];
}

// k1: conv1 (3ch -> 2ch) from precomputed Bx, then basis of outputs -> Bh.
__global__ __launch_bounds__(256) void k1_conv1(const float* __restrict__ Bx,
                                                const float* __restrict__ W1,
                                                float* __restrict__ Bh) {
    __shared__ float w[2 * 27 * 7];  // 378
    for (int i = threadIdx.x; i < 378; i += blockDim.x) w[i] = W1[i];
    __syncthreads();
    int p = blockIdx.x * blockDim.x + threadIdx.x;
    if (p >= NP1) return;
    int i = p / H1, j = p % H1;
    float acc0 = 0.f, acc1 = 0.f;
#pragma unroll
    for (int c = 0; c < 3; ++c)
#pragma unroll
        for (int di = 0; di < 3; ++di)
#pragma unroll
            for (int dj = 0; dj < 3; ++dj) {
                const float* b = &Bx[(((c * H0) + (i + di)) * H0 + (j + dj)) * 7];
                int e = c * 9 + di * 3 + dj;
                const float* w0 = &w[e * 7];
                const float* w1 = &w[189 + e * 7];
#pragma unroll
                for (int k = 0; k < 7; ++k) {
                    float bv = b[k];
                    acc0 += bv * w0[k];
                    acc1 += bv * w1[k];
                }
            }
    float B0[7], B1[7];
    bspline7(acc0, B0);
    bspline7(acc1, B1);
#pragma unroll
    for (int k = 0; k < 7; ++k) {
        Bh[(size_t)p * 7 + k] = B0[k];
        Bh[((size_t)NP1 + p) * 7 + k] = B1[k];
    }
}

// k2: conv2 (2ch -> 1ch) from Bh, then basis of output v -> Bv (flat e*7+k).
__global__ __launch_bounds__(256) void k2_conv2(const float* __restrict__ Bh,
                                                const float* __restrict__ W2,
                                                float* __restrict__ Bv) {
    __shared__ float w[18 * 7];  // 126
    for (int i = threadIdx.x; i < 126; i += blockDim.x) w[i] = W2[i];
    __syncthreads();
    int p = blockIdx.x * blockDim.x + threadIdx.x;
    if (p >= NP2) return;
    int i = p / H2, j = p % H2;
    float acc = 0.f;
#pragma unroll
    for (int c = 0; c < 2; ++c)
#pragma unroll
        for (int di = 0; di < 3; ++di)
#pragma unroll
            for (int dj = 0; dj < 3; ++dj) {
                const float* b = &Bh[((size_t)c * NP1 + (i + di) * H1 + (j + dj)) * 7];
                const float* we = &w[(c * 9 + di * 3 + dj) * 7];
#pragma unroll
                for (int k = 0; k < 7; ++k) acc += b[k] * we[k];
            }
    float B[7];
    bspline7(acc, B);
#pragma unroll
    for (int k = 0; k < 7; ++k) Bv[p * 7 + k] = B[k];
}

// k3: dense1 = 32 dot products of length L_DENSE. blockIdx.y = output row o.
__global__ __launch_bounds__(256) void k3_dense1(const float* __restrict__ W3,
                                                 const float* __restrict__ Bv,
                                                 float* __restrict__ acc32) {
    int o = blockIdx.y;
    const float4* w = (const float4*)(W3 + (size_t)o * L_DENSE);
    const float4* b = (const float4*)Bv;
    float s = 0.f;
    for (int f = blockIdx.x * blockDim.x + threadIdx.x; f < L4_DENSE;
         f += gridDim.x * blockDim.x) {
        float4 wv = w[f];
        float4 bv = b[f];
        s += wv.x * bv.x + wv.y * bv.y + wv.z * bv.z + wv.w * bv.w;
    }
    // wave reduce (64 lanes)
#pragma unroll
    for (int off = 32; off > 0; off >>= 1) s += __shfl_down(s, off, 64);
    __shared__ float ws[4];
    int wave = threadIdx.x >> 6;
    if ((threadIdx.x & 63) == 0) ws[wave] = s;
    __syncthreads();
    if (threadIdx.x == 0) {
        float bs = ws[0] + ws[1] + ws[2] + ws[3];
        atomicAdd(&acc32[o], bs);
    }
}

// k4: dense2 (32 -> 10), one small block.
__global__ void k4_dense2(const float* __restrict__ acc32, const float* __restrict__ W4,
                          float* __restrict__ out) {
    int o = threadIdx.x;
    if (o >= 10) return;
    float s = 0.f;
    for (int e = 0; e < 32; ++e) {
        float B[7];
        bspline7(acc32[e], B);
#pragma unroll
        for (int k = 0; k < 7; ++k) s += B[k] * W4[(o * 32 + e) * 7 + k];
    }
    out[o] = s;
}

extern "C" void kernel_launch(void* const* d_in, const int* in_sizes, int n_in,
                              void* d_out, int out_size, void* d_ws, size_t ws_size,
                              hipStream_t stream) {
    const float* x  = (const float*)d_in[0];   // [1,3,384,384]
    const float* W1 = (const float*)d_in[1];   // [2,27,7]
    const float* W2 = (const float*)d_in[2];   // [1,18,7]
    const float* W3 = (const float*)d_in[3];   // [32,144400,7]
    const float* W4 = (const float*)d_in[4];   // [10,32,7]
    float* out = (float*)d_out;                // [10]

    // workspace layout (16B aligned)
    char* ws = (char*)d_ws;
    float* acc32 = (float*)ws;                          // 128 B
    float* Bx = (float*)(ws + 128);                     // 12,386,304 B
    float* Bh = (float*)(ws + 128 + 12386304);          //  8,171,744 B
    float* Bv = (float*)(ws + 128 + 12386304 + 8171744);//  4,043,200 B (offset 20,558,176, 16B-aligned)

    k0_basis_x<<<(NX + 255) / 256, 256, 0, stream>>>(x, Bx, acc32);
    k1_conv1<<<(NP1 + 255) / 256, 256, 0, stream>>>(Bx, W1, Bh);
    k2_conv2<<<(NP2 + 255) / 256, 256, 0, stream>>>(Bh, W2, Bv);
    k3_dense1<<<dim3(64, 32), 256, 0, stream>>>(W3, Bv, acc32);
    k4_dense2<<<1, 64, 0, stream>>>(acc32, W4, out);
}